// Round 7
// baseline (345.393 us; speedup 1.0000x reference)
//
#include <hip/hip_runtime.h>
#include <hip/hip_bf16.h>

// MultiHeadSelfAttention: B=4, S=2048, D=1024, H=16, depth=64, eval mode.
// Inputs/outputs fp32 (per reference); internal compute bf16 MFMA + fp32 acc.
//
// Pipeline:
//   0) convert x fp32 -> xb bf16
//   1) transpose+convert weights -> WT bf16 (qkv concat, [3072][1024]), WoT
//   2) GEMM mode0: xb @ [Wq|Wk|Wv] + bias -> Q(*0.125*log2e,[B,H,S,64]),
//      K([B,H,S,64]), V^T([B,H,64,S] -> d_out[0,16M))
//   3) flash attention v12 -> O bf16 (d_out[16M,32M))
//   4) GEMM mode1: O @ Wo + bo + x(fp32 residual) -> Tmp BF16 [8192][1024]
//   5) layernorm(Tmp)*gamma+beta -> out fp32 (overwrites all of d_out)
//
// Flash history (counters):
//   v5 transient staging PROVEN 146 us; v7 merged q-tiles 139.6; v10 KV=64 +
//   O^T PV + transient staging 128.8 us (MfmaUtil 22, VALU 45, stall ~33%).
//   SPILL RULE (4x: v3/v8/v9/v11): DATA regs live across a barrier get
//   scratch-allocated -> 335-443 MB phantom writes. Transient-only staging.
//   v12: double-buffered K/V staged by global_load_lds DMA (NO data regs ->
//   spill rule not applicable). One __syncthreads per kt: its vmcnt(0) drain
//   is the pipeline wait; tile kt+1's DMA flies under tile kt's compute.
//   DMA needs linear LDS dest -> unpadded [64][64] tiles + both-sides XOR
//   swizzle (chunk col16 ^= row&7 on BOTH the per-lane global source and the
//   fragment reads) to keep K/V reads at the b128 bank floor.
//   TRIPWIRES: absmax must stay 0.03125 (swizzle); WRITE_SIZE 16384 (spill).
//
// GEMM history:
//   v1 (r7-proven): LDT=40 padded LDS, transient reg staging + prefetch.
//   v2 (r4): global_load_lds + LDT=32 -> REGRESSED (8-way frag-read bank
//       conflict at 64 B row stride; K=1024 can't amortize). REVERTED.
//   v3 (r5): + bijective XCD swizzle -> neutral (208-212 us both ways). KEPT.
//
// Workspace (56 MB total):
//   [0,        16777216)  xb  bf16 [8192][1024]   (dead after GEMM0)
//   [16777216, 23068672)  WT  bf16 [3072][1024]   (dead after GEMM0)
//   [23068672, 39845888)  Q   bf16                (dead after flash)
//   [39845888, 56623104)  K   bf16                (dead after flash)
//   [56623104, 58720256)  WoT bf16 [1024][1024]   (needed by GEMM1 -> placed last)
//   Tmp bf16 [0, 16777216) aliases dead xb when GEMM1 runs

typedef __bf16 bf16;
typedef __bf16 bf16x4 __attribute__((ext_vector_type(4)));
typedef __bf16 bf16x8 __attribute__((ext_vector_type(8)));
typedef float floatx4 __attribute__((ext_vector_type(4)));

#define MFMA16(a, b, c) __builtin_amdgcn_mfma_f32_16x16x32_bf16((a), (b), (c), 0, 0, 0)

static __device__ __forceinline__ floatx4 vmax4(floatx4 a, floatx4 b) {
    floatx4 r;
    r[0] = fmaxf(a[0], b[0]); r[1] = fmaxf(a[1], b[1]);
    r[2] = fmaxf(a[2], b[2]); r[3] = fmaxf(a[3], b[3]);
    return r;
}

// async global->LDS DMA, 16 B per lane: lane i's data lands at lds_base+i*16
// (wave-uniform LDS base, PER-LANE global address). No VGPRs hold the data.
// Counts in vmcnt; __syncthreads' vmcnt(0) drain is the completion wait.
// Correctness-proven in r4 (GEMM v2 passed absmax).
static __device__ __forceinline__ void gload16(const bf16* g, bf16* lds_base) {
    __builtin_amdgcn_global_load_lds(
        (__attribute__((address_space(1))) void*)(g),
        (__attribute__((address_space(3))) void*)(lds_base), 16, 0, 0);
}

// ---------------------------------------------------------------------------
// 0) fp32 -> bf16 convert (4 elems/thread)
__global__ __launch_bounds__(256) void convert_kernel(
    const float* __restrict__ x, bf16* __restrict__ xb)
{
    const int i = blockIdx.x * 256 + threadIdx.x;
    const float4 v = ((const float4*)x)[i];
    bf16x4 r;
    r[0] = (bf16)v.x; r[1] = (bf16)v.y; r[2] = (bf16)v.z; r[3] = (bf16)v.w;
    ((bf16x4*)xb)[i] = r;
}

// ---------------------------------------------------------------------------
// 1) 32x32 tiled transpose+convert: dst[n][k] = (bf16)src[k][n]; z picks W.
__global__ __launch_bounds__(256) void transpose_kernel(
    const float* __restrict__ Wq, const float* __restrict__ Wk,
    const float* __restrict__ Wv, const float* __restrict__ Wo,
    bf16* __restrict__ WT, bf16* __restrict__ WoT)
{
    __shared__ float tile[32][33];
    const int z = blockIdx.z;
    const float* src = (z == 0) ? Wq : (z == 1) ? Wk : (z == 2) ? Wv : Wo;
    bf16* dst = (z < 3) ? (WT + (long)z * 1024 * 1024) : WoT;
    const int n0 = blockIdx.x * 32, k0 = blockIdx.y * 32;
    const int tx = threadIdx.x & 31, ty = threadIdx.x >> 5;  // 8 rows x 32 cols
#pragma unroll
    for (int i = 0; i < 32; i += 8)
        tile[ty + i][tx] = src[(long)(k0 + ty + i) * 1024 + n0 + tx];
    __syncthreads();
#pragma unroll
    for (int i = 0; i < 32; i += 8)
        dst[(long)(n0 + ty + i) * 1024 + k0 + tx] = (bf16)tile[tx][ty + i];
}

// ---------------------------------------------------------------------------
// 2/4) GEMM C[M x N] = A[M x K] * Bt[N x K]^T, 128x128x32 tiles, 4 waves
// (r7-proven: padded LDS LDT=40, transient uint4 reg staging + persistent
// next-slab prefetch — clean in GEMM, unlike flash: lower reg pressure).
// Bijective XCD swizzle (nwg%8==0 both modes): XCD x gets contiguous work
// ids -> A-row panels / B matrix stay XCD-L2-local.
// MODE 0: N=3072, epilogue scatters to Q (*0.125*log2e folded), K, Vt w/ bias.
// MODE 1: N=1024, epilogue Tmp = bf16(C + bias + X residual).
template <int MODE>
__global__ __launch_bounds__(256, 2) void gemm_kernel(
    const bf16* __restrict__ A, const bf16* __restrict__ Bt,
    const float* __restrict__ b0, const float* __restrict__ b1,
    const float* __restrict__ b2, const float* __restrict__ X,
    bf16* __restrict__ Qo, bf16* __restrict__ Ko, bf16* __restrict__ Vto,
    bf16* __restrict__ Tmpb, int N, int K)
{
    constexpr int LDT = 40;  // 32 + 8 pad: keeps 16B alignment, breaks bank conflicts
    constexpr int NBX = (MODE == 0) ? 24 : 8;   // grid x-dim
    constexpr int NWG = NBX * 64;               // 1536 / 512, both % 8 == 0
    constexpr int CPX = NWG / 8;                // blocks per XCD chunk
    __shared__ __align__(16) bf16 As[128 * LDT];
    __shared__ __align__(16) bf16 Bs[128 * LDT];
    const int t = threadIdx.x;
    const int lane = t & 63;
    const int w = t >> 6;
    const int wm = w >> 1, wn = w & 1;  // 2x2 waves -> 64x64 each
    const int g = lane >> 4, c = lane & 15;

    // XCD-aware remap: HW id % 8 == XCD; give each XCD a contiguous chunk.
    const int id = blockIdx.y * NBX + blockIdx.x;
    const int swz = (id & 7) * CPX + (id >> 3);
    const int bm = (swz / NBX) * 128;
    const int bn = (swz % NBX) * 128;

    const int srow = t >> 2;        // 0..63
    const int scol = (t & 3) * 8;   // element offset (8 bf16 = 16B)

    floatx4 acc[4][4];
#pragma unroll
    for (int i = 0; i < 4; ++i)
#pragma unroll
        for (int j = 0; j < 4; ++j) acc[i][j] = floatx4{0.f, 0.f, 0.f, 0.f};

    const bf16* Ap0 = A + (long)(bm + srow) * K + scol;
    const bf16* Ap1 = A + (long)(bm + 64 + srow) * K + scol;
    const bf16* Bp0 = Bt + (long)(bn + srow) * K + scol;
    const bf16* Bp1 = Bt + (long)(bn + 64 + srow) * K + scol;

    uint4 a0 = *(const uint4*)(Ap0);
    uint4 a1 = *(const uint4*)(Ap1);
    uint4 q0 = *(const uint4*)(Bp0);
    uint4 q1 = *(const uint4*)(Bp1);

    for (int k0 = 0; k0 < K; k0 += 32) {
        __syncthreads();  // previous iteration's fragment reads are done
        *(uint4*)&As[srow * LDT + scol] = a0;
        *(uint4*)&As[(64 + srow) * LDT + scol] = a1;
        *(uint4*)&Bs[srow * LDT + scol] = q0;
        *(uint4*)&Bs[(64 + srow) * LDT + scol] = q1;
        __syncthreads();
        if (k0 + 32 < K) {  // prefetch next K-slab; overlaps MFMA below
            a0 = *(const uint4*)(Ap0 + k0 + 32);
            a1 = *(const uint4*)(Ap1 + k0 + 32);
            q0 = *(const uint4*)(Bp0 + k0 + 32);
            q1 = *(const uint4*)(Bp1 + k0 + 32);
        }
        bf16x8 af[4], bfv[4];
#pragma unroll
        for (int i = 0; i < 4; ++i)
            af[i] = *(const bf16x8*)&As[(wm * 64 + i * 16 + c) * LDT + g * 8];
#pragma unroll
        for (int j = 0; j < 4; ++j)
            bfv[j] = *(const bf16x8*)&Bs[(wn * 64 + j * 16 + c) * LDT + g * 8];
#pragma unroll
        for (int i = 0; i < 4; ++i)
#pragma unroll
            for (int j = 0; j < 4; ++j)
                acc[i][j] = MFMA16(af[i], bfv[j], acc[i][j]);
    }

    // Epilogue. C/D layout: col = c (lane&15), row = g*4 + reg.
    if (MODE == 0) {
#pragma unroll
        for (int j = 0; j < 4; ++j) {
            const int col = bn + wn * 64 + j * 16 + c;  // 0..3071
            const int sec = col >> 10;                  // 0=Q 1=K 2=V (uniform per j)
            const int nn = col & 1023;
            const int h = nn >> 6, dd = nn & 63;
            const float* bp = (sec == 0) ? b0 : (sec == 1) ? b1 : b2;
            const float bias = bp[nn];
#pragma unroll
            for (int i = 0; i < 4; ++i) {
                const int r0 = bm + wm * 64 + i * 16 + g * 4;
                if (sec == 2) {
                    bf16x4 pack;
#pragma unroll
                    for (int reg = 0; reg < 4; ++reg)
                        pack[reg] = (bf16)(acc[i][j][reg] + bias);
                    const int b_ = r0 >> 11, sr = r0 & 2047;  // r0 % 4 == 0, no 2048-cross
                    *(bf16x4*)&Vto[((long)(b_ * 16 + h) * 64 + dd) * 2048 + sr] = pack;
                } else {
#pragma unroll
                    for (int reg = 0; reg < 4; ++reg) {
                        const int r = r0 + reg;
                        const int b_ = r >> 11, sr = r & 2047;
                        const float v = acc[i][j][reg] + bias;
                        if (sec == 0)  // fold (1/8)*log2(e): softmax runs in exp2 domain
                            Qo[((long)(b_ * 16 + h) * 2048 + sr) * 64 + dd] =
                                (bf16)(v * 0.18033688011112042f);
                        else
                            Ko[((long)(b_ * 16 + h) * 2048 + sr) * 64 + dd] = (bf16)v;
                    }
                }
            }
        }
    } else {
#pragma unroll
        for (int j = 0; j < 4; ++j) {
            const int col = bn + wn * 64 + j * 16 + c;
            const float bias = b0[col];
#pragma unroll
            for (int i = 0; i < 4; ++i) {
#pragma unroll
                for (int reg = 0; reg < 4; ++reg) {
                    const int r = bm + wm * 64 + i * 16 + g * 4 + reg;
                    Tmpb[(long)r * N + col] =
                        (bf16)(acc[i][j][reg] + bias + X[(long)r * N + col]);
                }
            }
        }
    }
}

// ---------------------------------------------------------------------------
// 3) Flash attention v12: double-buffered K/V via global_load_lds DMA.
// LDS = KVs 32768 (2 dbuf x [K,V] x 64x64 unpadded) + Pl 18432 = 51200 B
// -> 3 blocks/CU (~= measured v10 occupancy; latency hiding now structural).
// Per kt: ONE __syncthreads (its vmcnt(0) drain = "tile kt staged by all
// waves" AND "dbuf[cur^1] free"); then issue kt+1's DMA into the other
// buffer (no data regs -> the 4x-confirmed spill rule can't trigger) and
// compute tile kt while the DMA flies.
// Swizzle (both-sides, rule #21): LDS tile = 64 rows x 8 chunks of 16 B,
// linear. DMA writes lane's chunk ch=(i*4+w)*64+lane; its GLOBAL source is
// chunk (row, col^(row&7)) (row=ch>>3, col=ch&7). Fragment reads XOR their
// 16B-chunk index with (row&7) -> see natural data, 8 lanes/4-bank group
// (the b128 floor). Spot-check: LDS chunk (9,3) <- global (9, 3^1=2);
// read wants (r=9,x=2) -> reads chunk (9, 2^1=3) -> global (9,2). OK.
// QK C layout: row g*4+r = kv, col c = q. PV accumulates O^T (C cols = q=c:
// rescale + 1/l lane-local, O store bf16x4). P via wave-private LDS rows.
// Grid (64 bh, 16 qt): head-major pins each head's blocks to one XCD.
__global__ __launch_bounds__(256, 2) void flash_kernel(
    const bf16* __restrict__ Q, const bf16* __restrict__ Kc,
    const bf16* __restrict__ Vt, bf16* __restrict__ O)
{
    constexpr int PSTR = 72;
    __shared__ __align__(16) bf16 KVs[2][2][64 * 64]; // [dbuf][0=K,1=V], 32768 B
    __shared__ __align__(16) bf16 Pl[4 * 32 * PSTR];  // 18432 B (32 rows/wave)
    const int t = threadIdx.x;
    const int lane = t & 63;
    const int w = t >> 6;
    const int g = lane >> 4, c = lane & 15;
    const int bh = blockIdx.x;           // head-major: XCD-local K/V
    const int b_ = bh >> 4, h = bh & 15;
    const bf16* Qp = Q + (long)bh * 2048 * 64;
    const bf16* Kp = Kc + (long)bh * 2048 * 64;
    const bf16* Vp = Vt + (long)bh * 64 * 2048;
    const int q0 = blockIdx.y * 128 + w * 32;
    bf16* Pw = Pl + w * 32 * PSTR;  // wave-private, 32 rows (16 per q-tile)

    // DMA staging geometry (kt-invariant; kt adds 4096 elems for K, 64 for V)
    const bf16* ksrc[2];
    const bf16* vsrc[2];
    int ldsoff[2];
#pragma unroll
    for (int i = 0; i < 2; ++i) {
        const int ch = (i * 4 + w) * 64 + lane;  // linear LDS chunk 0..511
        const int row = ch >> 3, col = ch & 7;
        const int sw = col ^ (row & 7);          // inverse-swizzled source col
        ksrc[i] = Kp + (long)(row * 8 + sw) * 8;          // K: [kv=row][d-chunk sw]
        vsrc[i] = Vp + (long)row * 2048 + sw * 8;         // V^T: [d=row][kv-chunk sw]
        ldsoff[i] = (i * 4 + w) * 512;                    // elems (chunk*8)
    }

    // Q fragments (B operand: n = q = c, k(depth) = g*8+j), whole-loop regs
    bf16x8 qf[2][2];
#pragma unroll
    for (int qs = 0; qs < 2; ++qs)
#pragma unroll
        for (int p = 0; p < 2; ++p)
            qf[qs][p] = *(const bf16x8*)(Qp + (long)(q0 + qs * 16 + c) * 64 + p * 32 + g * 8);

    float m_c[2] = {-1e30f, -1e30f};  // per-lane: q = qs*16 + c (g-uniform)
    float l_c[2] = {0.f, 0.f};
    floatx4 o[2][4];  // O^T: o[qs][dd][r] = O[q0+qs*16+c][h*64+dd*16+g*4+r]
#pragma unroll
    for (int qs = 0; qs < 2; ++qs)
#pragma unroll
        for (int dd = 0; dd < 4; ++dd) o[qs][dd] = floatx4{0.f, 0.f, 0.f, 0.f};

    // prologue: stage tile 0 into dbuf 0 (drained by loop-top barrier)
#pragma unroll
    for (int i = 0; i < 2; ++i) {
        gload16(ksrc[i], &KVs[0][0][ldsoff[i]]);
        gload16(vsrc[i], &KVs[0][1][ldsoff[i]]);
    }

    for (int kt = 0; kt < 32; ++kt) {
        // Compiler emits s_waitcnt vmcnt(0) lgkmcnt(0) before s_barrier:
        // tile kt's DMA (issued last iter) complete for ALL waves, and all
        // waves are done reading dbuf[cur^1] (tile kt-1) -> free to restage.
        __syncthreads();
        const int cur = kt & 1;
        if (kt + 1 < 32) {  // issue kt+1's DMA; flies under the compute below
#pragma unroll
            for (int i = 0; i < 2; ++i) {
                gload16(ksrc[i] + (long)(kt + 1) * 4096, &KVs[cur ^ 1][0][ldsoff[i]]);
                gload16(vsrc[i] + (long)(kt + 1) * 64,   &KVs[cur ^ 1][1][ldsoff[i]]);
            }
        }
        const bf16* KsB = KVs[cur][0];
        const bf16* VsB = KVs[cur][1];

        // S^T = K·Q^T for BOTH q-tiles off one K-frag load (swizzled reads).
        // C layout: row g*4+r = kv-in-tile, col c = q.
        const int r7 = c & 7;  // == row&7 of every row this lane reads (row%8 == c%8)
        floatx4 s[2][4];
#pragma unroll
        for (int ks = 0; ks < 4; ++ks) {
            bf16x8 kf0 = *(const bf16x8*)&KsB[(ks * 16 + c) * 64 + ((g ^ r7) << 3)];
            bf16x8 kf1 = *(const bf16x8*)&KsB[(ks * 16 + c) * 64 + (((g + 4) ^ r7) << 3)];
#pragma unroll
            for (int qs = 0; qs < 2; ++qs) {
                floatx4 z = floatx4{0.f, 0.f, 0.f, 0.f};
                z = MFMA16(kf0, qf[qs][0], z);
                z = MFMA16(kf1, qf[qs][1], z);
                s[qs][ks] = z;
            }
        }

        // online softmax per q-tile (v5-proven), P -> wave-private LDS rows
#pragma unroll
        for (int qs = 0; qs < 2; ++qs) {
            floatx4 t0 = vmax4(vmax4(s[qs][0], s[qs][1]), vmax4(s[qs][2], s[qs][3]));
            float mx = fmaxf(fmaxf(t0[0], t0[1]), fmaxf(t0[2], t0[3]));
            mx = fmaxf(mx, __shfl_xor(mx, 16, 64));
            mx = fmaxf(mx, __shfl_xor(mx, 32, 64));
            const float mn = fmaxf(m_c[qs], mx);
            const float al = __builtin_amdgcn_exp2f(m_c[qs] - mn);
            m_c[qs] = mn;
            floatx4 a4 = floatx4{0.f, 0.f, 0.f, 0.f};
#pragma unroll
            for (int ks = 0; ks < 4; ++ks) {
#pragma unroll
                for (int r = 0; r < 4; ++r)
                    s[qs][ks][r] = __builtin_amdgcn_exp2f(s[qs][ks][r] - mn);
                a4 += s[qs][ks];
            }
            float rs = (a4[0] + a4[1]) + (a4[2] + a4[3]);
            rs += __shfl_xor(rs, 16, 64);
            rs += __shfl_xor(rs, 32, 64);
            l_c[qs] = l_c[qs] * al + rs;
            // O^T cols are q=c: rescale directly, no al broadcast needed
#pragma unroll
            for (int dd = 0; dd < 4; ++dd)
#pragma unroll
                for (int r = 0; r < 4; ++r) o[qs][dd][r] *= al;
#pragma unroll
            for (int ks = 0; ks < 4; ++ks) {
                bf16x4 pk;
#pragma unroll
                for (int r = 0; r < 4; ++r) pk[r] = (bf16)s[qs][ks][r];
                *(bf16x4*)&Pw[(qs * 16 + c) * PSTR + ks * 16 + g * 4] = pk;
            }
        }
        asm volatile("s_waitcnt lgkmcnt(0)" ::: "memory");  // both P tiles visible
        // O^T += V^T·P^T for BOTH q-tiles off one V-frag load.
        // A = vf: V^T[d = dd*16+c][kv = kk*32+g*8+j] (swizzled); B = pf: P[q=c][kv].
#pragma unroll
        for (int kk = 0; kk < 2; ++kk) {
            bf16x8 pf0 = *(const bf16x8*)&Pw[(0 + c) * PSTR + kk * 32 + g * 8];
            bf16x8 pf1 = *(const bf16x8*)&Pw[(16 + c) * PSTR + kk * 32 + g * 8];
#pragma unroll
            for (int dd = 0; dd < 4; ++dd) {
                bf16x8 vf = *(const bf16x8*)&VsB[(dd * 16 + c) * 64 + (((kk * 4 + g) ^ r7) << 3)];
                o[0][dd] = MFMA16(vf, pf0, o[0][dd]);
                o[1][dd] = MFMA16(vf, pf1, o[1][dd]);
            }
        }
    }

    // epilogue: q = c matches l domain -> direct 1/l, vectorized store
#pragma unroll
    for (int qs = 0; qs < 2; ++qs) {
        const float linv = 1.0f / l_c[qs];
        const int q = q0 + qs * 16 + c;
#pragma unroll
        for (int dd = 0; dd < 4; ++dd) {
            bf16x4 pk;
#pragma unroll
            for (int r = 0; r < 4; ++r) pk[r] = (bf16)(o[qs][dd][r] * linv);
            *(bf16x4*)&O[((long)b_ * 2048 + q) * 1024 + h * 64 + dd * 16 + g * 4] = pk;
        }
    }
}

// ---------------------------------------------------------------------------
// 5) LayerNorm over rows of Tmp (bf16), one block per row, fp32 out.
__global__ __launch_bounds__(256, 2) void ln_kernel(
    const bf16* __restrict__ Tmp, const float* __restrict__ gamma,
    const float* __restrict__ beta, float* __restrict__ out)
{
    const int row = blockIdx.x;
    const int t = threadIdx.x;
    const int lane = t & 63, w = t >> 6;
    const bf16x4 vb = ((const bf16x4*)(Tmp + (long)row * 1024))[t];
    const float xv[4] = {(float)vb[0], (float)vb[1], (float)vb[2], (float)vb[3]};
    float s = xv[0] + xv[1] + xv[2] + xv[3];
    float ss = xv[0] * xv[0] + xv[1] * xv[1] + xv[2] * xv[2] + xv[3] * xv[3];
#pragma unroll
    for (int off = 1; off < 64; off <<= 1) {
        s += __shfl_xor(s, off, 64);
        ss += __shfl_xor(ss, off, 64);
    }
    __shared__ float sb[4], ssb[4];
    if (lane == 0) { sb[w] = s; ssb[w] = ss; }
    __syncthreads();
    s = sb[0] + sb[1] + sb[2] + sb[3];
    ss = ssb[0] + ssb[1] + ssb[2] + ssb[3];
    const float mu = s * (1.0f / 1024.0f);
    const float var = ss * (1.0f / 1024.0f) - mu * mu;
    const float inv = rsqrtf(var + 1e-6f);
    const float4 gm = ((const float4*)gamma)[t];
    const float4 bt = ((const float4*)beta)[t];
    float4 r;
    r.x = (xv[0] - mu) * inv * gm.x + bt.x;
    r.y = (xv[1] - mu) * inv * gm.y + bt.y;
    r.z = (xv[2] - mu) * inv * gm.z + bt.z;
    r.w = (xv[3] - mu) * inv * gm.w + bt.w;
    ((float4*)(out + (long)row * 1024))[t] = r;
}

// ---------------------------------------------------------------------------
extern "C" void kernel_launch(void* const* d_in, const int* in_sizes, int n_in,
                              void* d_out, int out_size, void* d_ws, size_t ws_size,
                              hipStream_t stream)
{
    const float* x     = (const float*)d_in[0];
    const float* Wq    = (const float*)d_in[1];
    const float* bq    = (const float*)d_in[2];
    const float* Wk    = (const float*)d_in[3];
    const float* bk    = (const float*)d_in[4];
    const float* Wv    = (const float*)d_in[5];
    const float* bv    = (const float*)d_in[6];
    const float* Wo    = (const float*)d_in[7];
    const float* bo    = (const float*)d_in[8];
    const float* gamma = (const float*)d_in[9];
    const float* beta  = (const float*)d_in[10];
    float* out = (float*)d_out;

    char* ws = (char*)d_ws;
    bf16* xb   = (bf16*)(ws);                   // [0, 16777216)
    bf16* WT   = (bf16*)(ws + 16777216);        // [16777216, 23068672)
    bf16* Qb   = (bf16*)(ws + 23068672);        // [23068672, 39845888)
    bf16* Kb   = (bf16*)(ws + 39845888);        // [39845888, 56623104)
    bf16* WoT  = (bf16*)(ws + 56623104);        // [56623104, 58720256)
    bf16* Tmpb = (bf16*)(ws);                   // [0, 16777216) alias dead xb
    bf16* Vtb  = (bf16*)d_out;                  // V^T parks in d_out[0, 16M)
    bf16* Ob   = (bf16*)((char*)d_out + 16777216);  // O parks in d_out[16M, 32M)

    convert_kernel<<<8192, 256, 0, stream>>>(x, xb);
    transpose_kernel<<<dim3(32, 32, 4), 256, 0, stream>>>(Wq, Wk, Wv, Wo, WT, WoT);
    gemm_kernel<0><<<dim3(24, 64), 256, 0, stream>>>(
        xb, WT, bq, bk, bv, nullptr, Qb, Kb, Vtb, nullptr, 3072, 1024);
    flash_kernel<<<dim3(64, 16), 256, 0, stream>>>(Qb, Kb, Vtb, Ob);
    gemm_kernel<1><<<dim3(8, 64), 256, 0, stream>>>(
        Ob, WoT, bo, nullptr, nullptr, x, nullptr, nullptr, nullptr, Tmpb, 1024, 1024);
    ln_kernel<<<8192, 256, 0, stream>>>(Tmpb, gamma, beta, out);
}

// Round 8
// 340.106 us; speedup vs baseline: 1.0155x; 1.0155x over previous
//
#include <hip/hip_runtime.h>
#include <hip/hip_bf16.h>

// MultiHeadSelfAttention: B=4, S=2048, D=1024, H=16, depth=64, eval mode.
// Inputs/outputs fp32 (per reference); internal compute bf16 MFMA + fp32 acc.
//
// Pipeline:
//   0) convert x fp32 -> xb bf16
//   1) transpose+convert weights -> WT bf16 (qkv concat, [3072][1024]), WoT
//   2) GEMM mode0: xb @ [Wq|Wk|Wv] + bias -> Q(*0.125*log2e,[B,H,S,64]),
//      K([B,H,S,64]), V^T([B,H,64,S] -> d_out[0,16M))
//   3) flash attention v10 -> O bf16 (d_out[16M,32M))
//   4) GEMM mode1: O @ Wo + bo + x(fp32 residual) -> Tmp BF16 [8192][1024]
//   5) layernorm(Tmp)*gamma+beta -> out fp32 (overwrites all of d_out)
//
// Flash history (counters):
//   v5 transient staging PROVEN 146; v7 merged q-tiles 139.6; v10 KV=64 +
//   O^T PV + transient staging -> 128.8 us BEST (MfmaUtil 22, VALU 45).
//   SPILL RULE (4x: v3/v8/v9/v11): DATA regs live across a barrier get
//   scratch-allocated -> 335-443 MB phantom writes. Transient-only staging.
//   v12 (r7): dbuf DMA pipeline -> 137.7 us. Swizzle CORRECT (absmax clean,
//   conflicts 14.7M->6.3M) but LDS 51200 -> 3 blocks/CU lost to occupancy.
//   dbuf+Pl cannot fit 4 blocks (>40960 B) -> branch closed. v10 restored.
//   BANK MODEL (corrected r7): wave-wide ds_read_b128 floor = 8 lanes per
//   16B slot (8 bank-cycles inherent). v10 padded reads already AT floor.
//
// GEMM history:
//   v1 (r7-proven): LDT=40 padded LDS, transient reg staging + prefetch.
//   v2 (r4): single-buffer gload_lds, 2 barriers -> +5 us. Diagnosis was
//       "bank conflicts" -- WRONG per corrected bank model (LDT=32 b128
//       reads are at the 8/slot floor). Real cause: exposed DMA latency
//       (no overlap, 2 blocks/CU TLP can't cover).
//   v3 (r5): + bijective XCD swizzle -> neutral. KEPT.
//   v5 (this round): T3 2-phase minimum (m97/m248-proven): LDS dbuf
//       (As/Bs x2, 32768 B), ONE barrier per k-step, next-slab DMA issued
//       after the barrier flies under the current slab's 64 MFMAs
//       (~400+ cy compute > ~300 cy L2 latency -> structural hiding).
//       No persistent regs (DMA writes LDS directly).
//       TRIPWIRE: if total >= 340 us, revert GEMM to v1 and plateau.
//
// Workspace (56 MB total):
//   [0,        16777216)  xb  bf16 [8192][1024]   (dead after GEMM0)
//   [16777216, 23068672)  WT  bf16 [3072][1024]   (dead after GEMM0)
//   [23068672, 39845888)  Q   bf16                (dead after flash)
//   [39845888, 56623104)  K   bf16                (dead after flash)
//   [56623104, 58720256)  WoT bf16 [1024][1024]   (needed by GEMM1 -> placed last)
//   Tmp bf16 [0, 16777216) aliases dead xb when GEMM1 runs

typedef __bf16 bf16;
typedef __bf16 bf16x4 __attribute__((ext_vector_type(4)));
typedef __bf16 bf16x8 __attribute__((ext_vector_type(8)));
typedef float floatx4 __attribute__((ext_vector_type(4)));

#define MFMA16(a, b, c) __builtin_amdgcn_mfma_f32_16x16x32_bf16((a), (b), (c), 0, 0, 0)

static __device__ __forceinline__ floatx4 vmax4(floatx4 a, floatx4 b) {
    floatx4 r;
    r[0] = fmaxf(a[0], b[0]); r[1] = fmaxf(a[1], b[1]);
    r[2] = fmaxf(a[2], b[2]); r[3] = fmaxf(a[3], b[3]);
    return r;
}

// async global->LDS DMA, 16 B per lane: lane i's data lands at lds_base+i*16
// (wave-uniform LDS base, PER-LANE global address). No VGPRs hold the data.
// Counts in vmcnt; __syncthreads' vmcnt(0) drain is the completion wait.
static __device__ __forceinline__ void gload16(const bf16* g, bf16* lds_base) {
    __builtin_amdgcn_global_load_lds(
        (__attribute__((address_space(1))) void*)(g),
        (__attribute__((address_space(3))) void*)(lds_base), 16, 0, 0);
}

// ---------------------------------------------------------------------------
// 0) fp32 -> bf16 convert (4 elems/thread)
__global__ __launch_bounds__(256) void convert_kernel(
    const float* __restrict__ x, bf16* __restrict__ xb)
{
    const int i = blockIdx.x * 256 + threadIdx.x;
    const float4 v = ((const float4*)x)[i];
    bf16x4 r;
    r[0] = (bf16)v.x; r[1] = (bf16)v.y; r[2] = (bf16)v.z; r[3] = (bf16)v.w;
    ((bf16x4*)xb)[i] = r;
}

// ---------------------------------------------------------------------------
// 1) 32x32 tiled transpose+convert: dst[n][k] = (bf16)src[k][n]; z picks W.
__global__ __launch_bounds__(256) void transpose_kernel(
    const float* __restrict__ Wq, const float* __restrict__ Wk,
    const float* __restrict__ Wv, const float* __restrict__ Wo,
    bf16* __restrict__ WT, bf16* __restrict__ WoT)
{
    __shared__ float tile[32][33];
    const int z = blockIdx.z;
    const float* src = (z == 0) ? Wq : (z == 1) ? Wk : (z == 2) ? Wv : Wo;
    bf16* dst = (z < 3) ? (WT + (long)z * 1024 * 1024) : WoT;
    const int n0 = blockIdx.x * 32, k0 = blockIdx.y * 32;
    const int tx = threadIdx.x & 31, ty = threadIdx.x >> 5;  // 8 rows x 32 cols
#pragma unroll
    for (int i = 0; i < 32; i += 8)
        tile[ty + i][tx] = src[(long)(k0 + ty + i) * 1024 + n0 + tx];
    __syncthreads();
#pragma unroll
    for (int i = 0; i < 32; i += 8)
        dst[(long)(n0 + ty + i) * 1024 + k0 + tx] = (bf16)tile[tx][ty + i];
}

// ---------------------------------------------------------------------------
// 2/4) GEMM C[M x N] = A[M x K] * Bt[N x K]^T, 128x128x32 tiles, 4 waves.
// v5: T3 2-phase DMA pipeline (m97/m248-proven form): LDS double-buffer,
// ONE barrier per k-step; the barrier's vmcnt(0) drain completes the DMA
// issued LAST iteration (which had the whole 64-MFMA compute to fly under).
// LDT=32 linear (gload_lds needs contiguous dest; b128 frag reads at the
// 8-lanes/16B-slot floor per the corrected bank model).
// Staging: chunk ch=(i*4+w)*64+lane -> row=ch>>2, col16=ch&3; per-lane
// global source A[(bm+row)*K + k0 + (ch&3)*8]; wave-uniform LDS base.
// Bijective XCD swizzle (nwg%8==0 both modes) kept.
// MODE 0: N=3072, epilogue scatters to Q (*0.125*log2e folded), K, Vt w/ bias.
// MODE 1: N=1024, epilogue Tmp = bf16(C + bias + X residual).
template <int MODE>
__global__ __launch_bounds__(256, 2) void gemm_kernel(
    const bf16* __restrict__ A, const bf16* __restrict__ Bt,
    const float* __restrict__ b0, const float* __restrict__ b1,
    const float* __restrict__ b2, const float* __restrict__ X,
    bf16* __restrict__ Qo, bf16* __restrict__ Ko, bf16* __restrict__ Vto,
    bf16* __restrict__ Tmpb, int N, int K)
{
    constexpr int LDT = 32;
    constexpr int NBX = (MODE == 0) ? 24 : 8;   // grid x-dim
    constexpr int NWG = NBX * 64;               // 1536 / 512, both % 8 == 0
    constexpr int CPX = NWG / 8;                // blocks per XCD chunk
    __shared__ __align__(16) bf16 As[2][128 * LDT];  // 2 x 8192 B
    __shared__ __align__(16) bf16 Bs[2][128 * LDT];  // 2 x 8192 B
    const int t = threadIdx.x;
    const int lane = t & 63;
    const int w = t >> 6;
    const int wm = w >> 1, wn = w & 1;  // 2x2 waves -> 64x64 each
    const int g = lane >> 4, c = lane & 15;

    // XCD-aware remap: HW id % 8 == XCD; give each XCD a contiguous chunk.
    const int id = blockIdx.y * NBX + blockIdx.x;
    const int swz = (id & 7) * CPX + (id >> 3);
    const int bm = (swz / NBX) * 128;
    const int bn = (swz % NBX) * 128;

    // DMA staging geometry (k-invariant): 512 chunks per matrix, 2 issues.
    const bf16* asrc[2];
    const bf16* bsrc[2];
    int ldsoff[2];
#pragma unroll
    for (int i = 0; i < 2; ++i) {
        const int ch = (i * 4 + w) * 64 + lane;   // 0..511
        const int row = ch >> 2, col = ch & 3;
        asrc[i] = A + (long)(bm + row) * K + col * 8;
        bsrc[i] = Bt + (long)(bn + row) * K + col * 8;
        ldsoff[i] = (i * 4 + w) * 512;            // elems
    }

    floatx4 acc[4][4];
#pragma unroll
    for (int i = 0; i < 4; ++i)
#pragma unroll
        for (int j = 0; j < 4; ++j) acc[i][j] = floatx4{0.f, 0.f, 0.f, 0.f};

    // prologue: stage slab 0 into buf 0 (drained by first loop-top barrier)
#pragma unroll
    for (int i = 0; i < 2; ++i) {
        gload16(asrc[i], &As[0][ldsoff[i]]);
        gload16(bsrc[i], &Bs[0][ldsoff[i]]);
    }

    int cur = 0;
    for (int k0 = 0; k0 < K; k0 += 32) {
        // vmcnt(0)+lgkmcnt(0) drain at barrier: buf[cur] staged for all
        // waves AND all waves done reading buf[cur^1] -> free to restage.
        __syncthreads();
        if (k0 + 32 < K) {  // issue next slab's DMA; flies under MFMAs below
#pragma unroll
            for (int i = 0; i < 2; ++i) {
                gload16(asrc[i] + k0 + 32, &As[cur ^ 1][ldsoff[i]]);
                gload16(bsrc[i] + k0 + 32, &Bs[cur ^ 1][ldsoff[i]]);
            }
        }
        bf16x8 af[4], bfv[4];
#pragma unroll
        for (int i = 0; i < 4; ++i)
            af[i] = *(const bf16x8*)&As[cur][(wm * 64 + i * 16 + c) * LDT + g * 8];
#pragma unroll
        for (int j = 0; j < 4; ++j)
            bfv[j] = *(const bf16x8*)&Bs[cur][(wn * 64 + j * 16 + c) * LDT + g * 8];
#pragma unroll
        for (int i = 0; i < 4; ++i)
#pragma unroll
            for (int j = 0; j < 4; ++j)
                acc[i][j] = MFMA16(af[i], bfv[j], acc[i][j]);
        cur ^= 1;
    }

    // Epilogue. C/D layout: col = c (lane&15), row = g*4 + reg.
    if (MODE == 0) {
#pragma unroll
        for (int j = 0; j < 4; ++j) {
            const int col = bn + wn * 64 + j * 16 + c;  // 0..3071
            const int sec = col >> 10;                  // 0=Q 1=K 2=V (uniform per j)
            const int nn = col & 1023;
            const int h = nn >> 6, dd = nn & 63;
            const float* bp = (sec == 0) ? b0 : (sec == 1) ? b1 : b2;
            const float bias = bp[nn];
#pragma unroll
            for (int i = 0; i < 4; ++i) {
                const int r0 = bm + wm * 64 + i * 16 + g * 4;
                if (sec == 2) {
                    bf16x4 pack;
#pragma unroll
                    for (int reg = 0; reg < 4; ++reg)
                        pack[reg] = (bf16)(acc[i][j][reg] + bias);
                    const int b_ = r0 >> 11, sr = r0 & 2047;  // r0 % 4 == 0, no 2048-cross
                    *(bf16x4*)&Vto[((long)(b_ * 16 + h) * 64 + dd) * 2048 + sr] = pack;
                } else {
#pragma unroll
                    for (int reg = 0; reg < 4; ++reg) {
                        const int r = r0 + reg;
                        const int b_ = r >> 11, sr = r & 2047;
                        const float v = acc[i][j][reg] + bias;
                        if (sec == 0)  // fold (1/8)*log2(e): softmax runs in exp2 domain
                            Qo[((long)(b_ * 16 + h) * 2048 + sr) * 64 + dd] =
                                (bf16)(v * 0.18033688011112042f);
                        else
                            Ko[((long)(b_ * 16 + h) * 2048 + sr) * 64 + dd] = (bf16)v;
                    }
                }
            }
        }
    } else {
#pragma unroll
        for (int j = 0; j < 4; ++j) {
            const int col = bn + wn * 64 + j * 16 + c;
            const float bias = b0[col];
#pragma unroll
            for (int i = 0; i < 4; ++i) {
#pragma unroll
                for (int reg = 0; reg < 4; ++reg) {
                    const int r = bm + wm * 64 + i * 16 + g * 4 + reg;
                    Tmpb[(long)r * N + col] =
                        (bf16)(acc[i][j][reg] + bias + X[(long)r * N + col]);
                }
            }
        }
    }
}

// ---------------------------------------------------------------------------
// 3) Flash attention v10 (measured best: 128.8 us): KV=64 tiles (LDS =
// Ks 9216 + Vs 9216 + Pl 18432 = 36864 B -> 4 blocks/CU = 16 waves/CU) +
// O^T PV + v7-proven TRANSIENT staging (kr/vr live ONLY inside the barrier
// pair; cross-barrier staging regs get scratch-allocated -> 335-443 MB
// phantom writes, 4x-confirmed: v3/v8/v9/v11).
// PV accumulates O^T: o[qs][dd] = MFMA(A=V^T-frag, B=P^T-frag): C cols = q=c
// -> alpha rescale and 1/l need no shfl transport, O store is bf16x4.
// Grid (64 bh, 16 qt): head-major pins each head's blocks to one XCD.
// 4 waves/block, 32 q-rows each; 1024 blocks = exactly 4/CU x 256 CU.
__global__ __launch_bounds__(256, 2) void flash_kernel(
    const bf16* __restrict__ Q, const bf16* __restrict__ Kc,
    const bf16* __restrict__ Vt, bf16* __restrict__ O)
{
    constexpr int KSTR = 72;   // 64 + 8 pad (bf16)
    constexpr int VSTR = 72;
    constexpr int PSTR = 72;
    __shared__ __align__(16) bf16 Ks[64 * KSTR];     // 9216 B
    __shared__ __align__(16) bf16 Vs[64 * VSTR];     // 9216 B
    __shared__ __align__(16) bf16 Pl[4 * 32 * PSTR]; // 18432 B (32 rows/wave)
    const int t = threadIdx.x;
    const int lane = t & 63;
    const int w = t >> 6;
    const int g = lane >> 4, c = lane & 15;
    const int bh = blockIdx.x;           // head-major: XCD-local K/V
    const int b_ = bh >> 4, h = bh & 15;
    const bf16* Qp = Q + (long)bh * 2048 * 64;
    const bf16* Kp = Kc + (long)bh * 2048 * 64;
    const bf16* Vp = Vt + (long)bh * 64 * 2048;
    const int q0 = blockIdx.y * 128 + w * 32;
    bf16* Pw = Pl + w * 32 * PSTR;  // wave-private, 32 rows (16 per q-tile)

    // Q fragments (B operand: n = q = c, k(depth) = g*8+j), whole-loop regs
    bf16x8 qf[2][2];
#pragma unroll
    for (int qs = 0; qs < 2; ++qs)
#pragma unroll
        for (int p = 0; p < 2; ++p)
            qf[qs][p] = *(const bf16x8*)(Qp + (long)(q0 + qs * 16 + c) * 64 + p * 32 + g * 8);

    float m_c[2] = {-1e30f, -1e30f};  // per-lane: q = qs*16 + c (g-uniform)
    float l_c[2] = {0.f, 0.f};
    floatx4 o[2][4];  // O^T: o[qs][dd][r] = O[q0+qs*16+c][h*64+dd*16+g*4+r]
#pragma unroll
    for (int qs = 0; qs < 2; ++qs)
#pragma unroll
        for (int dd = 0; dd < 4; ++dd) o[qs][dd] = floatx4{0.f, 0.f, 0.f, 0.f};

    for (int kt = 0; kt < 32; ++kt) {
        __syncthreads();  // all waves done reading tiles of kt-1
        {   // transient staging: regs live only inside this barrier pair
            uint4 kr[2], vr[2];
#pragma unroll
            for (int i = 0; i < 2; ++i) {
                const int idx = i * 256 + t;  // 0..511
                kr[i] = *(const uint4*)(Kp + (long)kt * 4096 + idx * 8);
                vr[i] = *(const uint4*)(Vp + (long)(idx >> 3) * 2048 + kt * 64 + (idx & 7) * 8);
            }
#pragma unroll
            for (int i = 0; i < 2; ++i) {
                const int idx = i * 256 + t;
                *(uint4*)&Ks[(idx >> 3) * KSTR + (idx & 7) * 8] = kr[i];
                *(uint4*)&Vs[(idx >> 3) * VSTR + (idx & 7) * 8] = vr[i];
            }
        }
        __syncthreads();

        // S^T = K·Q^T for BOTH q-tiles off one K-frag load.
        // C layout: row g*4+r = kv-in-tile, col c = q.
        floatx4 s[2][4];
#pragma unroll
        for (int ks = 0; ks < 4; ++ks) {
            bf16x8 kf0 = *(const bf16x8*)&Ks[(ks * 16 + c) * KSTR + g * 8];
            bf16x8 kf1 = *(const bf16x8*)&Ks[(ks * 16 + c) * KSTR + 32 + g * 8];
#pragma unroll
            for (int qs = 0; qs < 2; ++qs) {
                floatx4 z = floatx4{0.f, 0.f, 0.f, 0.f};
                z = MFMA16(kf0, qf[qs][0], z);
                z = MFMA16(kf1, qf[qs][1], z);
                s[qs][ks] = z;
            }
        }

        // online softmax per q-tile (v5-proven), P -> wave-private LDS rows
#pragma unroll
        for (int qs = 0; qs < 2; ++qs) {
            floatx4 t0 = vmax4(vmax4(s[qs][0], s[qs][1]), vmax4(s[qs][2], s[qs][3]));
            float mx = fmaxf(fmaxf(t0[0], t0[1]), fmaxf(t0[2], t0[3]));
            mx = fmaxf(mx, __shfl_xor(mx, 16, 64));
            mx = fmaxf(mx, __shfl_xor(mx, 32, 64));
            const float mn = fmaxf(m_c[qs], mx);
            const float al = __builtin_amdgcn_exp2f(m_c[qs] - mn);
            m_c[qs] = mn;
            floatx4 a4 = floatx4{0.f, 0.f, 0.f, 0.f};
#pragma unroll
            for (int ks = 0; ks < 4; ++ks) {
#pragma unroll
                for (int r = 0; r < 4; ++r)
                    s[qs][ks][r] = __builtin_amdgcn_exp2f(s[qs][ks][r] - mn);
                a4 += s[qs][ks];
            }
            float rs = (a4[0] + a4[1]) + (a4[2] + a4[3]);
            rs += __shfl_xor(rs, 16, 64);
            rs += __shfl_xor(rs, 32, 64);
            l_c[qs] = l_c[qs] * al + rs;
            // O^T cols are q=c: rescale directly, no al broadcast needed
#pragma unroll
            for (int dd = 0; dd < 4; ++dd)
#pragma unroll
                for (int r = 0; r < 4; ++r) o[qs][dd][r] *= al;
#pragma unroll
            for (int ks = 0; ks < 4; ++ks) {
                bf16x4 pk;
#pragma unroll
                for (int r = 0; r < 4; ++r) pk[r] = (bf16)s[qs][ks][r];
                *(bf16x4*)&Pw[(qs * 16 + c) * PSTR + ks * 16 + g * 4] = pk;
            }
        }
        asm volatile("s_waitcnt lgkmcnt(0)" ::: "memory");  // both P tiles visible
        // O^T += V^T·P^T for BOTH q-tiles off one V-frag load.
        // A = vf: V^T[d = dd*16+c][kv = kk*32+g*8+j]; B = pf: P[q=c][kv].
#pragma unroll
        for (int kk = 0; kk < 2; ++kk) {
            bf16x8 pf0 = *(const bf16x8*)&Pw[(0 + c) * PSTR + kk * 32 + g * 8];
            bf16x8 pf1 = *(const bf16x8*)&Pw[(16 + c) * PSTR + kk * 32 + g * 8];
#pragma unroll
            for (int dd = 0; dd < 4; ++dd) {
                bf16x8 vf = *(const bf16x8*)&Vs[(dd * 16 + c) * VSTR + kk * 32 + g * 8];
                o[0][dd] = MFMA16(vf, pf0, o[0][dd]);
                o[1][dd] = MFMA16(vf, pf1, o[1][dd]);
            }
        }
    }

    // epilogue: q = c matches l domain -> direct 1/l, vectorized store
#pragma unroll
    for (int qs = 0; qs < 2; ++qs) {
        const float linv = 1.0f / l_c[qs];
        const int q = q0 + qs * 16 + c;
#pragma unroll
        for (int dd = 0; dd < 4; ++dd) {
            bf16x4 pk;
#pragma unroll
            for (int r = 0; r < 4; ++r) pk[r] = (bf16)(o[qs][dd][r] * linv);
            *(bf16x4*)&O[((long)b_ * 2048 + q) * 1024 + h * 64 + dd * 16 + g * 4] = pk;
        }
    }
}

// ---------------------------------------------------------------------------
// 5) LayerNorm over rows of Tmp (bf16), one block per row, fp32 out.
__global__ __launch_bounds__(256, 2) void ln_kernel(
    const bf16* __restrict__ Tmp, const float* __restrict__ gamma,
    const float* __restrict__ beta, float* __restrict__ out)
{
    const int row = blockIdx.x;
    const int t = threadIdx.x;
    const int lane = t & 63, w = t >> 6;
    const bf16x4 vb = ((const bf16x4*)(Tmp + (long)row * 1024))[t];
    const float xv[4] = {(float)vb[0], (float)vb[1], (float)vb[2], (float)vb[3]};
    float s = xv[0] + xv[1] + xv[2] + xv[3];
    float ss = xv[0] * xv[0] + xv[1] * xv[1] + xv[2] * xv[2] + xv[3] * xv[3];
#pragma unroll
    for (int off = 1; off < 64; off <<= 1) {
        s += __shfl_xor(s, off, 64);
        ss += __shfl_xor(ss, off, 64);
    }
    __shared__ float sb[4], ssb[4];
    if (lane == 0) { sb[w] = s; ssb[w] = ss; }
    __syncthreads();
    s = sb[0] + sb[1] + sb[2] + sb[3];
    ss = ssb[0] + ssb[1] + ssb[2] + ssb[3];
    const float mu = s * (1.0f / 1024.0f);
    const float var = ss * (1.0f / 1024.0f) - mu * mu;
    const float inv = rsqrtf(var + 1e-6f);
    const float4 gm = ((const float4*)gamma)[t];
    const float4 bt = ((const float4*)beta)[t];
    float4 r;
    r.x = (xv[0] - mu) * inv * gm.x + bt.x;
    r.y = (xv[1] - mu) * inv * gm.y + bt.y;
    r.z = (xv[2] - mu) * inv * gm.z + bt.z;
    r.w = (xv[3] - mu) * inv * gm.w + bt.w;
    ((float4*)(out + (long)row * 1024))[t] = r;
}

// ---------------------------------------------------------------------------
extern "C" void kernel_launch(void* const* d_in, const int* in_sizes, int n_in,
                              void* d_out, int out_size, void* d_ws, size_t ws_size,
                              hipStream_t stream)
{
    const float* x     = (const float*)d_in[0];
    const float* Wq    = (const float*)d_in[1];
    const float* bq    = (const float*)d_in[2];
    const float* Wk    = (const float*)d_in[3];
    const float* bk    = (const float*)d_in[4];
    const float* Wv    = (const float*)d_in[5];
    const float* bv    = (const float*)d_in[6];
    const float* Wo    = (const float*)d_in[7];
    const float* bo    = (const float*)d_in[8];
    const float* gamma = (const float*)d_in[9];
    const float* beta  = (const float*)d_in[10];
    float* out = (float*)d_out;

    char* ws = (char*)d_ws;
    bf16* xb   = (bf16*)(ws);                   // [0, 16777216)
    bf16* WT   = (bf16*)(ws + 16777216);        // [16777216, 23068672)
    bf16* Qb   = (bf16*)(ws + 23068672);        // [23068672, 39845888)
    bf16* Kb   = (bf16*)(ws + 39845888);        // [39845888, 56623104)
    bf16* WoT  = (bf16*)(ws + 56623104);        // [56623104, 58720256)
    bf16* Tmpb = (bf16*)(ws);                   // [0, 16777216) alias dead xb
    bf16* Vtb  = (bf16*)d_out;                  // V^T parks in d_out[0, 16M)
    bf16* Ob   = (bf16*)((char*)d_out + 16777216);  // O parks in d_out[16M, 32M)

    convert_kernel<<<8192, 256, 0, stream>>>(x, xb);
    transpose_kernel<<<dim3(32, 32, 4), 256, 0, stream>>>(Wq, Wk, Wv, Wo, WT, WoT);
    gemm_kernel<0><<<dim3(24, 64), 256, 0, stream>>>(
        xb, WT, bq, bk, bv, nullptr, Qb, Kb, Vtb, nullptr, 3072, 1024);
    flash_kernel<<<dim3(64, 16), 256, 0, stream>>>(Qb, Kb, Vtb, Ob);
    gemm_kernel<1><<<dim3(8, 64), 256, 0, stream>>>(
        Ob, WoT, bo, nullptr, nullptr, x, nullptr, nullptr, nullptr, Tmpb, 1024, 1024);
    ln_kernel<<<8192, 256, 0, stream>>>(Tmpb, gamma, beta, out);
}

// Round 9
// 324.976 us; speedup vs baseline: 1.0628x; 1.0466x over previous
//
#include <hip/hip_runtime.h>
#include <hip/hip_bf16.h>

// MultiHeadSelfAttention: B=4, S=2048, D=1024, H=16, depth=64, eval mode.
// Inputs/outputs fp32 (per reference); internal compute bf16 MFMA + fp32 acc.
//
// Pipeline:
//   0) convert x fp32 -> xb bf16
//   1) transpose+convert weights -> WT bf16 (qkv concat, [3072][1024]), WoT
//   2) GEMM mode0: xb @ [Wq|Wk|Wv] + bias -> Q(*0.125*log2e,[B,H,S,64]),
//      K([B,H,S,64]), V^T([B,H,64,S] -> d_out[0,16M))
//   3) flash attention v13 -> O bf16 (d_out[16M,32M))
//   4) GEMM mode1: O @ Wo + bo + x(fp32 residual) -> Tmp BF16 [8192][1024]
//   5) layernorm(Tmp)*gamma+beta -> out fp32 (overwrites all of d_out)
//
// Flash history (counters):
//   v5 transient staging 146; v7 merged q-tiles 139.6; v10 KV=64 + O^T PV +
//   transient staging 128.8 BEST-so-far (MfmaUtil 22, VALU 45, ~33% stall:
//   staging serialized between 2 barriers).
//   SPILL RULE (4x: v3/v8/v9/v11): DATA regs live across a barrier get
//   scratch-allocated -> 335-443 MB phantom writes. Transient-only staging.
//   v12 (r7): dbuf DMA pipeline -> 137.7. Swizzle+pipeline CORRECT (absmax
//   clean, conflicts 14.7M->6.3M) but Pl pushed LDS to 51200 -> 3 blocks/CU.
//   v13: 32x32 MFMA restructure removes Pl entirely: QK C-layout gives each
//   lane P[q=lane&31][kv=(reg&3)+8(reg>>2)+4hw]; PV B-frag needs only a
//   lane<->lane+32 exchange (8 shfl_xor(32)/kt, T12 pattern). LDS = dbuf
//   KV only = 32768 -> 4 blocks/CU AND the v12 pipeline. MFMA cycles/kt
//   160->128 (8+8 32x32x16 @8cyc vs 16+16 16x16x32 @5cyc). Single m/l,
//   one shfl_xor softmax reduce.
//   TRIPWIRES: absmax 0.03125 (layout); WRITE_SIZE 16384 (spill).
//   Fallback: r8's v10 flash.
//
// GEMM history:
//   v1: LDT=40 reg staging + prefetch. v2 (r4): 1-buf gload_lds REGRESSED
//   (exposed DMA latency, NOT bank conflicts -- corrected bank model r7:
//   b128 floor = 8 lanes/16B slot). v3: XCD swizzle, neutral, kept.
//   v5 (r8): 2-phase DMA dbuf, one barrier/k-step == v1 within noise. KEPT.
//
// Workspace (56 MB total):
//   [0,        16777216)  xb  bf16 [8192][1024]   (dead after GEMM0)
//   [16777216, 23068672)  WT  bf16 [3072][1024]   (dead after GEMM0)
//   [23068672, 39845888)  Q   bf16                (dead after flash)
//   [39845888, 56623104)  K   bf16                (dead after flash)
//   [56623104, 58720256)  WoT bf16 [1024][1024]   (needed by GEMM1 -> placed last)
//   Tmp bf16 [0, 16777216) aliases dead xb when GEMM1 runs

typedef __bf16 bf16;
typedef __bf16 bf16x2 __attribute__((ext_vector_type(2)));
typedef __bf16 bf16x4 __attribute__((ext_vector_type(4)));
typedef __bf16 bf16x8 __attribute__((ext_vector_type(8)));
typedef float floatx4 __attribute__((ext_vector_type(4)));
typedef float floatx16 __attribute__((ext_vector_type(16)));

#define MFMA16(a, b, c) __builtin_amdgcn_mfma_f32_16x16x32_bf16((a), (b), (c), 0, 0, 0)
#define MFMA32(a, b, c) __builtin_amdgcn_mfma_f32_32x32x16_bf16((a), (b), (c), 0, 0, 0)

// async global->LDS DMA, 16 B per lane: lane i's data lands at lds_base+i*16
// (wave-uniform LDS base, PER-LANE global address). No VGPRs hold the data.
// Counts in vmcnt; __syncthreads' vmcnt(0) drain is the completion wait.
static __device__ __forceinline__ void gload16(const bf16* g, bf16* lds_base) {
    __builtin_amdgcn_global_load_lds(
        (__attribute__((address_space(1))) void*)(g),
        (__attribute__((address_space(3))) void*)(lds_base), 16, 0, 0);
}

// ---------------------------------------------------------------------------
// 0) fp32 -> bf16 convert (4 elems/thread)
__global__ __launch_bounds__(256) void convert_kernel(
    const float* __restrict__ x, bf16* __restrict__ xb)
{
    const int i = blockIdx.x * 256 + threadIdx.x;
    const float4 v = ((const float4*)x)[i];
    bf16x4 r;
    r[0] = (bf16)v.x; r[1] = (bf16)v.y; r[2] = (bf16)v.z; r[3] = (bf16)v.w;
    ((bf16x4*)xb)[i] = r;
}

// ---------------------------------------------------------------------------
// 1) 32x32 tiled transpose+convert: dst[n][k] = (bf16)src[k][n]; z picks W.
__global__ __launch_bounds__(256) void transpose_kernel(
    const float* __restrict__ Wq, const float* __restrict__ Wk,
    const float* __restrict__ Wv, const float* __restrict__ Wo,
    bf16* __restrict__ WT, bf16* __restrict__ WoT)
{
    __shared__ float tile[32][33];
    const int z = blockIdx.z;
    const float* src = (z == 0) ? Wq : (z == 1) ? Wk : (z == 2) ? Wv : Wo;
    bf16* dst = (z < 3) ? (WT + (long)z * 1024 * 1024) : WoT;
    const int n0 = blockIdx.x * 32, k0 = blockIdx.y * 32;
    const int tx = threadIdx.x & 31, ty = threadIdx.x >> 5;  // 8 rows x 32 cols
#pragma unroll
    for (int i = 0; i < 32; i += 8)
        tile[ty + i][tx] = src[(long)(k0 + ty + i) * 1024 + n0 + tx];
    __syncthreads();
#pragma unroll
    for (int i = 0; i < 32; i += 8)
        dst[(long)(n0 + ty + i) * 1024 + k0 + tx] = (bf16)tile[tx][ty + i];
}

// ---------------------------------------------------------------------------
// 2/4) GEMM C[M x N] = A[M x K] * Bt[N x K]^T, 128x128x32 tiles, 4 waves.
// v5 (r8-proven): T3 2-phase DMA pipeline: LDS double-buffer, ONE barrier
// per k-step; the barrier's vmcnt(0) drain completes the DMA issued LAST
// iteration (which had the whole 64-MFMA compute to fly under). LDT=32
// linear (b128 frag reads at the 8-lanes/16B-slot floor).
// Bijective XCD swizzle (nwg%8==0 both modes) kept.
// MODE 0: N=3072, epilogue scatters to Q (*0.125*log2e folded), K, Vt w/ bias.
// MODE 1: N=1024, epilogue Tmp = bf16(C + bias + X residual).
template <int MODE>
__global__ __launch_bounds__(256, 2) void gemm_kernel(
    const bf16* __restrict__ A, const bf16* __restrict__ Bt,
    const float* __restrict__ b0, const float* __restrict__ b1,
    const float* __restrict__ b2, const float* __restrict__ X,
    bf16* __restrict__ Qo, bf16* __restrict__ Ko, bf16* __restrict__ Vto,
    bf16* __restrict__ Tmpb, int N, int K)
{
    constexpr int LDT = 32;
    constexpr int NBX = (MODE == 0) ? 24 : 8;   // grid x-dim
    constexpr int NWG = NBX * 64;               // 1536 / 512, both % 8 == 0
    constexpr int CPX = NWG / 8;                // blocks per XCD chunk
    __shared__ __align__(16) bf16 As[2][128 * LDT];  // 2 x 8192 B
    __shared__ __align__(16) bf16 Bs[2][128 * LDT];  // 2 x 8192 B
    const int t = threadIdx.x;
    const int lane = t & 63;
    const int w = t >> 6;
    const int wm = w >> 1, wn = w & 1;  // 2x2 waves -> 64x64 each
    const int g = lane >> 4, c = lane & 15;

    // XCD-aware remap: HW id % 8 == XCD; give each XCD a contiguous chunk.
    const int id = blockIdx.y * NBX + blockIdx.x;
    const int swz = (id & 7) * CPX + (id >> 3);
    const int bm = (swz / NBX) * 128;
    const int bn = (swz % NBX) * 128;

    // DMA staging geometry (k-invariant): 512 chunks per matrix, 2 issues.
    const bf16* asrc[2];
    const bf16* bsrc[2];
    int ldsoff[2];
#pragma unroll
    for (int i = 0; i < 2; ++i) {
        const int ch = (i * 4 + w) * 64 + lane;   // 0..511
        const int row = ch >> 2, col = ch & 3;
        asrc[i] = A + (long)(bm + row) * K + col * 8;
        bsrc[i] = Bt + (long)(bn + row) * K + col * 8;
        ldsoff[i] = (i * 4 + w) * 512;            // elems
    }

    floatx4 acc[4][4];
#pragma unroll
    for (int i = 0; i < 4; ++i)
#pragma unroll
        for (int j = 0; j < 4; ++j) acc[i][j] = floatx4{0.f, 0.f, 0.f, 0.f};

    // prologue: stage slab 0 into buf 0 (drained by first loop-top barrier)
#pragma unroll
    for (int i = 0; i < 2; ++i) {
        gload16(asrc[i], &As[0][ldsoff[i]]);
        gload16(bsrc[i], &Bs[0][ldsoff[i]]);
    }

    int cur = 0;
    for (int k0 = 0; k0 < K; k0 += 32) {
        // vmcnt(0)+lgkmcnt(0) drain at barrier: buf[cur] staged for all
        // waves AND all waves done reading buf[cur^1] -> free to restage.
        __syncthreads();
        if (k0 + 32 < K) {  // issue next slab's DMA; flies under MFMAs below
#pragma unroll
            for (int i = 0; i < 2; ++i) {
                gload16(asrc[i] + k0 + 32, &As[cur ^ 1][ldsoff[i]]);
                gload16(bsrc[i] + k0 + 32, &Bs[cur ^ 1][ldsoff[i]]);
            }
        }
        bf16x8 af[4], bfv[4];
#pragma unroll
        for (int i = 0; i < 4; ++i)
            af[i] = *(const bf16x8*)&As[cur][(wm * 64 + i * 16 + c) * LDT + g * 8];
#pragma unroll
        for (int j = 0; j < 4; ++j)
            bfv[j] = *(const bf16x8*)&Bs[cur][(wn * 64 + j * 16 + c) * LDT + g * 8];
#pragma unroll
        for (int i = 0; i < 4; ++i)
#pragma unroll
            for (int j = 0; j < 4; ++j)
                acc[i][j] = MFMA16(af[i], bfv[j], acc[i][j]);
        cur ^= 1;
    }

    // Epilogue. C/D layout: col = c (lane&15), row = g*4 + reg.
    if (MODE == 0) {
#pragma unroll
        for (int j = 0; j < 4; ++j) {
            const int col = bn + wn * 64 + j * 16 + c;  // 0..3071
            const int sec = col >> 10;                  // 0=Q 1=K 2=V (uniform per j)
            const int nn = col & 1023;
            const int h = nn >> 6, dd = nn & 63;
            const float* bp = (sec == 0) ? b0 : (sec == 1) ? b1 : b2;
            const float bias = bp[nn];
#pragma unroll
            for (int i = 0; i < 4; ++i) {
                const int r0 = bm + wm * 64 + i * 16 + g * 4;
                if (sec == 2) {
                    bf16x4 pack;
#pragma unroll
                    for (int reg = 0; reg < 4; ++reg)
                        pack[reg] = (bf16)(acc[i][j][reg] + bias);
                    const int b_ = r0 >> 11, sr = r0 & 2047;  // r0 % 4 == 0, no 2048-cross
                    *(bf16x4*)&Vto[((long)(b_ * 16 + h) * 64 + dd) * 2048 + sr] = pack;
                } else {
#pragma unroll
                    for (int reg = 0; reg < 4; ++reg) {
                        const int r = r0 + reg;
                        const int b_ = r >> 11, sr = r & 2047;
                        const float v = acc[i][j][reg] + bias;
                        if (sec == 0)  // fold (1/8)*log2(e): softmax runs in exp2 domain
                            Qo[((long)(b_ * 16 + h) * 2048 + sr) * 64 + dd] =
                                (bf16)(v * 0.18033688011112042f);
                        else
                            Ko[((long)(b_ * 16 + h) * 2048 + sr) * 64 + dd] = (bf16)v;
                    }
                }
            }
        }
    } else {
#pragma unroll
        for (int j = 0; j < 4; ++j) {
            const int col = bn + wn * 64 + j * 16 + c;
            const float bias = b0[col];
#pragma unroll
            for (int i = 0; i < 4; ++i) {
#pragma unroll
                for (int reg = 0; reg < 4; ++reg) {
                    const int r = bm + wm * 64 + i * 16 + g * 4 + reg;
                    Tmpb[(long)r * N + col] =
                        (bf16)(acc[i][j][reg] + bias + X[(long)r * N + col]);
                }
            }
        }
    }
}

// ---------------------------------------------------------------------------
// 3) Flash attention v13: 32x32 MFMA + v12 DMA-dbuf pipeline, no P LDS.
// LDS = KVs dbuf only = 32768 B -> 4 blocks/CU. One barrier per kt (its
// vmcnt(0) drain = tile ready + other dbuf free); kt+1's DMA flies under
// kt's compute. Swizzle (proven r7): LDS[row][colL] = global[row][colL ^
// (row&7)] in 16B chunks; reads XOR chunk idx with (row&7).
// Per wave: 32 q rows (q = q0w + lane&31). QK: S^T[kv][q], A=K-frag,
// B=Q-frag, 2 kv-tiles x 4 depth-slabs = 8 MFMA32. C layout: col=lane&31=q,
// row kv = (reg&3)+8*(reg>>2)+4*hw (hw=lane>>5). Softmax: all 32 kv of a
// q-row live in lanes {l, l^32} -> 1 shfl_xor(32) reduce; single m/l.
// P: pack reg pairs to bf16x2 dwords dpk[tile][u] (kv = 2(u&1)+8(u>>1)+4hw);
// PV B-frag pb[slab] (kv run slab*16+hw*8..+7) = 2 own dwords + 2 from
// partner lane via shfl_xor(32) with hw-selected source expr (derivation in
// session notes; all 4 (hw,slab) cases verified). PV: O^T[d][q], A=V^T-frag,
// B=pb, 2 d-tiles x 4 slabs = 8 MFMA32. Epilogue: q=lane&31 matches l
// domain -> direct 1/l, bf16x4 stores (d = dt*32+rg*8+hw*4+r).
// Grid (64 bh, 16 qt): head-major pins each head's blocks to one XCD.
__global__ __launch_bounds__(256, 2) void flash_kernel(
    const bf16* __restrict__ Q, const bf16* __restrict__ Kc,
    const bf16* __restrict__ Vt, bf16* __restrict__ O)
{
    __shared__ __align__(16) bf16 KVs[2][2][64 * 64]; // [dbuf][0=K,1=V] 32768 B
    const int t = threadIdx.x;
    const int lane = t & 63;
    const int w = t >> 6;
    const int l31 = lane & 31, hw = lane >> 5;
    const int bh = blockIdx.x;           // head-major: XCD-local K/V
    const int b_ = bh >> 4, h = bh & 15;
    const bf16* Qp = Q + (long)bh * 2048 * 64;
    const bf16* Kp = Kc + (long)bh * 2048 * 64;
    const bf16* Vp = Vt + (long)bh * 64 * 2048;
    const int q0w = blockIdx.y * 128 + w * 32;

    // DMA staging geometry (kt-invariant; kt adds 4096 elems for K, 64 for V)
    const bf16* ksrc[2];
    const bf16* vsrc[2];
    int ldsoff[2];
#pragma unroll
    for (int i = 0; i < 2; ++i) {
        const int ch = (i * 4 + w) * 64 + lane;  // linear LDS chunk 0..511
        const int row = ch >> 3, col = ch & 7;
        const int sw = col ^ (row & 7);          // inverse-swizzled source col
        ksrc[i] = Kp + (long)(row * 8 + sw) * 8;      // K: [kv=row][d-chunk sw]
        vsrc[i] = Vp + (long)row * 2048 + sw * 8;     // V^T: [d=row][kv-chunk sw]
        ldsoff[i] = (i * 4 + w) * 512;                // elems (chunk*8)
    }

    // Q fragments (B operand: n=q=l31, k-run = slab*16 + hw*8), whole-loop
    bf16x8 qf[4];
#pragma unroll
    for (int sl = 0; sl < 4; ++sl)
        qf[sl] = *(const bf16x8*)(Qp + (long)(q0w + l31) * 64 + sl * 16 + hw * 8);

    float m_c = -1e30f;  // per-lane: q = l31 (hw-uniform via shfl merge)
    float l_c = 0.f;
    floatx16 o32[2];     // O^T[d = dt*32 + (reg&3)+8(reg>>2)+4hw][q = l31]
#pragma unroll
    for (int dt = 0; dt < 2; ++dt)
#pragma unroll
        for (int i = 0; i < 16; ++i) o32[dt][i] = 0.f;

    // prologue: stage tile 0 into dbuf 0 (drained by loop-top barrier)
#pragma unroll
    for (int i = 0; i < 2; ++i) {
        gload16(ksrc[i], &KVs[0][0][ldsoff[i]]);
        gload16(vsrc[i], &KVs[0][1][ldsoff[i]]);
    }

    for (int kt = 0; kt < 32; ++kt) {
        // vmcnt(0)+lgkmcnt(0) drain at barrier: tile kt staged for all
        // waves AND all waves done with dbuf[cur^1] -> free to restage.
        __syncthreads();
        const int cur = kt & 1;
        if (kt + 1 < 32) {  // issue kt+1's DMA; flies under compute below
#pragma unroll
            for (int i = 0; i < 2; ++i) {
                gload16(ksrc[i] + (long)(kt + 1) * 4096, &KVs[cur ^ 1][0][ldsoff[i]]);
                gload16(vsrc[i] + (long)(kt + 1) * 64,   &KVs[cur ^ 1][1][ldsoff[i]]);
            }
        }
        const bf16* KsB = KVs[cur][0];
        const bf16* VsB = KVs[cur][1];

        // QK: S^T[kv][q] over 2 kv-tiles, 4 depth slabs (swizzled K reads)
        floatx16 s32[2];
#pragma unroll
        for (int kt_ = 0; kt_ < 2; ++kt_)
#pragma unroll
            for (int i = 0; i < 16; ++i) s32[kt_][i] = 0.f;
#pragma unroll
        for (int sl = 0; sl < 4; ++sl) {
            const int x = sl * 2 + hw;          // depth 16B-chunk
            const int r0 = l31, r1 = 32 + l31;  // r0&7 == r1&7
            const int xs = x ^ (r0 & 7);
            bf16x8 kf0 = *(const bf16x8*)&KsB[r0 * 64 + (xs << 3)];
            bf16x8 kf1 = *(const bf16x8*)&KsB[r1 * 64 + (xs << 3)];
            s32[0] = MFMA32(kf0, qf[sl], s32[0]);
            s32[1] = MFMA32(kf1, qf[sl], s32[1]);
        }

        // online softmax: all 32 kv of q-row in {lane, lane^32}
        float mx;
        {
            float tm[16];
#pragma unroll
            for (int i = 0; i < 16; ++i) tm[i] = fmaxf(s32[0][i], s32[1][i]);
            float a0 = fmaxf(fmaxf(tm[0], tm[1]), fmaxf(tm[2], tm[3]));
            float a1 = fmaxf(fmaxf(tm[4], tm[5]), fmaxf(tm[6], tm[7]));
            float a2 = fmaxf(fmaxf(tm[8], tm[9]), fmaxf(tm[10], tm[11]));
            float a3 = fmaxf(fmaxf(tm[12], tm[13]), fmaxf(tm[14], tm[15]));
            mx = fmaxf(fmaxf(a0, a1), fmaxf(a2, a3));
        }
        mx = fmaxf(mx, __shfl_xor(mx, 32, 64));
        const float mn = fmaxf(m_c, mx);
        const float al = __builtin_amdgcn_exp2f(m_c - mn);
        m_c = mn;
        float r0s = 0.f, r1s = 0.f, r2s = 0.f, r3s = 0.f;
#pragma unroll
        for (int kt_ = 0; kt_ < 2; ++kt_) {
#pragma unroll
            for (int i = 0; i < 16; i += 4) {
                s32[kt_][i + 0] = __builtin_amdgcn_exp2f(s32[kt_][i + 0] - mn);
                s32[kt_][i + 1] = __builtin_amdgcn_exp2f(s32[kt_][i + 1] - mn);
                s32[kt_][i + 2] = __builtin_amdgcn_exp2f(s32[kt_][i + 2] - mn);
                s32[kt_][i + 3] = __builtin_amdgcn_exp2f(s32[kt_][i + 3] - mn);
                r0s += s32[kt_][i + 0]; r1s += s32[kt_][i + 1];
                r2s += s32[kt_][i + 2]; r3s += s32[kt_][i + 3];
            }
        }
        float rs = (r0s + r1s) + (r2s + r3s);
        rs += __shfl_xor(rs, 32, 64);
        l_c = l_c * al + rs;
#pragma unroll
        for (int dt = 0; dt < 2; ++dt)
#pragma unroll
            for (int i = 0; i < 16; ++i) o32[dt][i] *= al;

        // pack P to bf16 dwords: dpk[tile][u] = kv pair 2(u&1)+8(u>>1)+4hw
        uint32_t dpk[2][8];
#pragma unroll
        for (int kt_ = 0; kt_ < 2; ++kt_)
#pragma unroll
            for (int u = 0; u < 8; ++u) {
                bf16x2 p2;
                p2[0] = (bf16)s32[kt_][2 * u];
                p2[1] = (bf16)s32[kt_][2 * u + 1];
                dpk[kt_][u] = __builtin_bit_cast(uint32_t, p2);
            }

        // PV B-frags pb[slab]: kv run slab*16 + hw*8 .. +7. Own 2 dwords +
        // 2 from partner (lane^32); source expr hw-selected so the partner
        // provides what THIS half needs (verified all 4 (hw,slab) cases).
        bf16x8 pb[4];
#pragma unroll
        for (int sl = 0; sl < 4; ++sl) {
            const int kt_ = sl >> 1;
            const int ub = (sl & 1) * 4;
            const uint32_t eA = hw ? dpk[kt_][ub + 0] : dpk[kt_][ub + 2];
            const uint32_t eB = hw ? dpk[kt_][ub + 1] : dpk[kt_][ub + 3];
            const uint32_t rA = (uint32_t)__shfl_xor((int)eA, 32, 64);
            const uint32_t rB = (uint32_t)__shfl_xor((int)eB, 32, 64);
            uint4 fr;
            if (hw == 0)
                fr = make_uint4(dpk[kt_][ub + 0], dpk[kt_][ub + 1], rA, rB);
            else
                fr = make_uint4(rA, rB, dpk[kt_][ub + 2], dpk[kt_][ub + 3]);
            pb[sl] = __builtin_bit_cast(bf16x8, fr);
        }

        // PV: O^T[d][q] += V^T-frag x pb, 2 d-tiles x 4 kv-slabs (swizzled V)
#pragma unroll
        for (int sl = 0; sl < 4; ++sl) {
            const int x = sl * 2 + hw;  // kv 16B-chunk
#pragma unroll
            for (int dt = 0; dt < 2; ++dt) {
                const int row = dt * 32 + l31;
                bf16x8 vf = *(const bf16x8*)&VsB[row * 64 + ((x ^ (row & 7)) << 3)];
                o32[dt] = MFMA32(vf, pb[sl], o32[dt]);
            }
        }
    }

    // epilogue: q = l31 matches l domain -> direct 1/l, bf16x4 stores
    const float linv = 1.0f / l_c;
    const int q = q0w + l31;
#pragma unroll
    for (int dt = 0; dt < 2; ++dt)
#pragma unroll
        for (int rg = 0; rg < 4; ++rg) {
            bf16x4 pk;
#pragma unroll
            for (int r = 0; r < 4; ++r) pk[r] = (bf16)(o32[dt][rg * 4 + r] * linv);
            const int d0 = dt * 32 + rg * 8 + hw * 4;
            *(bf16x4*)&O[((long)b_ * 2048 + q) * 1024 + h * 64 + d0] = pk;
        }
}

// ---------------------------------------------------------------------------
// 5) LayerNorm over rows of Tmp (bf16), one block per row, fp32 out.
__global__ __launch_bounds__(256, 2) void ln_kernel(
    const bf16* __restrict__ Tmp, const float* __restrict__ gamma,
    const float* __restrict__ beta, float* __restrict__ out)
{
    const int row = blockIdx.x;
    const int t = threadIdx.x;
    const int lane = t & 63, w = t >> 6;
    const bf16x4 vb = ((const bf16x4*)(Tmp + (long)row * 1024))[t];
    const float xv[4] = {(float)vb[0], (float)vb[1], (float)vb[2], (float)vb[3]};
    float s = xv[0] + xv[1] + xv[2] + xv[3];
    float ss = xv[0] * xv[0] + xv[1] * xv[1] + xv[2] * xv[2] + xv[3] * xv[3];
#pragma unroll
    for (int off = 1; off < 64; off <<= 1) {
        s += __shfl_xor(s, off, 64);
        ss += __shfl_xor(ss, off, 64);
    }
    __shared__ float sb[4], ssb[4];
    if (lane == 0) { sb[w] = s; ssb[w] = ss; }
    __syncthreads();
    s = sb[0] + sb[1] + sb[2] + sb[3];
    ss = ssb[0] + ssb[1] + ssb[2] + ssb[3];
    const float mu = s * (1.0f / 1024.0f);
    const float var = ss * (1.0f / 1024.0f) - mu * mu;
    const float inv = rsqrtf(var + 1e-6f);
    const float4 gm = ((const float4*)gamma)[t];
    const float4 bt = ((const float4*)beta)[t];
    float4 r;
    r.x = (xv[0] - mu) * inv * gm.x + bt.x;
    r.y = (xv[1] - mu) * inv * gm.y + bt.y;
    r.z = (xv[2] - mu) * inv * gm.z + bt.z;
    r.w = (xv[3] - mu) * inv * gm.w + bt.w;
    ((float4*)(out + (long)row * 1024))[t] = r;
}

// ---------------------------------------------------------------------------
extern "C" void kernel_launch(void* const* d_in, const int* in_sizes, int n_in,
                              void* d_out, int out_size, void* d_ws, size_t ws_size,
                              hipStream_t stream)
{
    const float* x     = (const float*)d_in[0];
    const float* Wq    = (const float*)d_in[1];
    const float* bq    = (const float*)d_in[2];
    const float* Wk    = (const float*)d_in[3];
    const float* bk    = (const float*)d_in[4];
    const float* Wv    = (const float*)d_in[5];
    const float* bv    = (const float*)d_in[6];
    const float* Wo    = (const float*)d_in[7];
    const float* bo    = (const float*)d_in[8];
    const float* gamma = (const float*)d_in[9];
    const float* beta  = (const float*)d_in[10];
    float* out = (float*)d_out;

    char* ws = (char*)d_ws;
    bf16* xb   = (bf16*)(ws);                   // [0, 16777216)
    bf16* WT   = (bf16*)(ws + 16777216);        // [16777216, 23068672)
    bf16* Qb   = (bf16*)(ws + 23068672);        // [23068672, 39845888)
    bf16* Kb   = (bf16*)(ws + 39845888);        // [39845888, 56623104)
    bf16* WoT  = (bf16*)(ws + 56623104);        // [56623104, 58720256)
    bf16* Tmpb = (bf16*)(ws);                   // [0, 16777216) alias dead xb
    bf16* Vtb  = (bf16*)d_out;                  // V^T parks in d_out[0, 16M)
    bf16* Ob   = (bf16*)((char*)d_out + 16777216);  // O parks in d_out[16M, 32M)

    convert_kernel<<<8192, 256, 0, stream>>>(x, xb);
    transpose_kernel<<<dim3(32, 32, 4), 256, 0, stream>>>(Wq, Wk, Wv, Wo, WT, WoT);
    gemm_kernel<0><<<dim3(24, 64), 256, 0, stream>>>(
        xb, WT, bq, bk, bv, nullptr, Qb, Kb, Vtb, nullptr, 3072, 1024);
    flash_kernel<<<dim3(64, 16), 256, 0, stream>>>(Qb, Kb, Vtb, Ob);
    gemm_kernel<1><<<dim3(8, 64), 256, 0, stream>>>(
        Ob, WoT, bo, nullptr, nullptr, x, nullptr, nullptr, nullptr, Tmpb, 1024, 1024);
    ln_kernel<<<8192, 256, 0, stream>>>(Tmpb, gamma, beta, out);
}